// Round 8
// baseline (120.356 us; speedup 1.0000x reference)
//
#include <hip/hip_runtime.h>
#include <hip/hip_bf16.h>
#include <math.h>

// Problem constants (B=4096, D=128, T=0.5 -> 1/T = 2)
#define BB       4096
#define N2       8192          // 2B rows of z
#define DIMS     128
#define NT       64            // number of 128-row tiles per matrix side
#define NJOBS    (NT * (NT + 1) / 2)   // 2080 upper-triangle tile jobs
#define TILE     128

// z rows are pre-scaled by ZSCALE so the MFMA dot directly yields
// sim * 2*log2(e), i.e. exp(sim/T) = exp2(acc). ZSCALE^2 = 2.8853900818.
#define ZSCALE   1.6986436f
// diagonal term exp(2 * |z_r|^2) ~= exp(2) — subtracted in reduce.
#define DIAG_E2  7.38905609893065f

typedef __attribute__((ext_vector_type(8))) short short8;   // 8 x bf16 (4 VGPRs)
typedef __attribute__((ext_vector_type(4))) float float4v;  // MFMA C/D

// ---------------------------------------------------------------------------
// Kernel 1: normalize rows (fp32), compute positives (fp32), write z as
// bf16 scaled by ZSCALE. Zeroes out[0] (reduce accumulates into it).
// One wave per row-pair r: emb_i[r] -> z[r], emb_j[r] -> z[r+B].
// (r7 post-mortem: normalization must happen ONCE — fusing it into the sim
// blocks redid it 33x and cost ~12 µs of VALU.)
// ---------------------------------------------------------------------------
__global__ __launch_bounds__(256) void norm_kernel(
    const float* __restrict__ emb_i, const float* __restrict__ emb_j,
    __hip_bfloat16* __restrict__ z, float* __restrict__ pos,
    float* __restrict__ out) {
  if (blockIdx.x == 0 && threadIdx.x == 0) out[0] = 0.0f;

  int gw   = (blockIdx.x * blockDim.x + threadIdx.x) >> 6;  // row pair
  int lane = threadIdx.x & 63;
  if (gw >= BB) return;

  const float2* ei = (const float2*)(emb_i + (size_t)gw * DIMS);
  const float2* ej = (const float2*)(emb_j + (size_t)gw * DIMS);
  float2 a = ei[lane];
  float2 b = ej[lane];

  float sa = a.x * a.x + a.y * a.y;
  float sb = b.x * b.x + b.y * b.y;
  #pragma unroll
  for (int m = 32; m; m >>= 1) {
    sa += __shfl_xor(sa, m, 64);
    sb += __shfl_xor(sb, m, 64);
  }
  float inva = 1.0f / fmaxf(sqrtf(sa), 1e-12f);
  float invb = 1.0f / fmaxf(sqrtf(sb), 1e-12f);

  float zi0 = a.x * inva, zi1 = a.y * inva;
  float zj0 = b.x * invb, zj1 = b.y * invb;

  // positive pair dot in unscaled fp32 (matches reference's fp32 einsum)
  float p = zi0 * zj0 + zi1 * zj1;
  #pragma unroll
  for (int m = 32; m; m >>= 1) p += __shfl_xor(p, m, 64);
  if (lane == 0) pos[gw] = p;

  __hip_bfloat162* zr_i = (__hip_bfloat162*)(z + (size_t)gw * DIMS);
  __hip_bfloat162* zr_j = (__hip_bfloat162*)(z + (size_t)(gw + BB) * DIMS);
  __hip_bfloat162 vi, vj;
  vi.x = __float2bfloat16(zi0 * ZSCALE); vi.y = __float2bfloat16(zi1 * ZSCALE);
  vj.x = __float2bfloat16(zj0 * ZSCALE); vj.y = __float2bfloat16(zj1 * ZSCALE);
  zr_i[lane] = vi;
  zr_j[lane] = vj;
}

// ---------------------------------------------------------------------------
// Kernel 2: symmetric sim-GEMM + exp2, NO LDS, NO BARRIERS.
// r7 counters (first direct measurement): all pipes <28%, occupancy 31%,
// per-block latency ~13 µs for ~2-4K cycles of work => the block-wide
// serial chain (A-load -> B-stage -> barrier -> t-loop -> barrier) was the
// bottleneck, not any pipe. This version makes every wave independent:
//  * wave w of block (I,J) owns rows R0+w*32..+32 (same mapping as r6);
//  * B-fragments are loaded DIRECTLY from global z at exactly the addresses
//    the r6 LDS reads resolved to (bit-identical MFMA inputs); the 32 KB
//    B-tile is L1-resident after first touch (4 waves/CU share it);
//  * col-partials go to a private Pc[J][I][wave][:] slice (no LDS combine,
//    no atomics); reduce folds the 4 wave slices.
// Row-partials P[I][J][w*32..] written disjointly per wave as before.
// ---------------------------------------------------------------------------
__global__ __launch_bounds__(256, 4) void simloss_sym(
    const __hip_bfloat16* __restrict__ z, float* __restrict__ P,
    float* __restrict__ Pc) {
  const int tid  = threadIdx.x;
  const int wave = tid >> 6;
  const int lane = tid & 63;
  const int lr   = lane & 15;          // A-row / B-col / C-col within tile
  const int quad = lane >> 4;          // k-group for A/B, row-group for C

  // ---- decode flat job id -> (I, J) with I <= J over NT=64 ----
  const int j = blockIdx.x;
  int I = (int)((129.0f - sqrtf(16641.0f - 8.0f * (float)j)) * 0.5f);
  I = I < 0 ? 0 : (I > NT - 1 ? NT - 1 : I);
  while (I < NT - 1 && (I + 1) * (2 * NT - I) / 2 <= j) ++I;
  while (I > 0 && I * (2 * NT - I + 1) / 2 > j) --I;
  const int J = I + (j - I * (2 * NT - I + 1) / 2);
  const bool diag = (I == J);
  const int R0 = I * TILE;
  const int C0 = J * TILE;

  const ushort* zp = (const ushort*)z;

  // ---- A fragments pinned in VGPRs: rows R0 + wave*32 + rt*16 + lr ----
  short8 afrag[2][4];
  #pragma unroll
  for (int rt = 0; rt < 2; rt++) {
    const int arow = R0 + wave * 32 + rt * 16 + lr;
    const short8* ap = (const short8*)(zp + (size_t)arow * DIMS + quad * 8);
    afrag[rt][0] = ap[0];
    afrag[rt][1] = ap[4];   // +32 shorts
    afrag[rt][2] = ap[8];
    afrag[rt][3] = ap[12];
  }

  float rowsum[2][4];
  #pragma unroll
  for (int rt = 0; rt < 2; rt++)
    #pragma unroll
    for (int r = 0; r < 4; r++) rowsum[rt][r] = 0.0f;

  #pragma unroll 4
  for (int t = 0; t < 8; t++) {        // 8 column tiles of 16
    // B fragment straight from global: col C0 + t*16 + lr, k = quad*8 + ...
    // (identical addresses to the r6 LDS reads -> bit-identical MFMA inputs)
    const short8* bp =
        (const short8*)(zp + (size_t)(C0 + t * 16 + lr) * DIMS + quad * 8);
    short8 b0 = bp[0];
    short8 b1 = bp[4];
    short8 b2 = bp[8];
    short8 b3 = bp[12];
    float ctile = 0.0f;
    #pragma unroll
    for (int rt = 0; rt < 2; rt++) {
      float4v acc = {0.0f, 0.0f, 0.0f, 0.0f};
      acc = __builtin_amdgcn_mfma_f32_16x16x32_bf16(afrag[rt][0], b0, acc, 0, 0, 0);
      acc = __builtin_amdgcn_mfma_f32_16x16x32_bf16(afrag[rt][1], b1, acc, 0, 0, 0);
      acc = __builtin_amdgcn_mfma_f32_16x16x32_bf16(afrag[rt][2], b2, acc, 0, 0, 0);
      acc = __builtin_amdgcn_mfma_f32_16x16x32_bf16(afrag[rt][3], b3, acc, 0, 0, 0);
      // exp(sim/T) = exp2(acc) thanks to ZSCALE pre-scaling.
      #pragma unroll
      for (int r = 0; r < 4; r++) {
        float e = __builtin_amdgcn_exp2f(acc[r]);
        rowsum[rt][r] += e;
        ctile += e;
      }
    }
    if (!diag) {  // block-uniform branch
      // col sums over this wave's 32 rows (4 C-regs above + quads via xor)
      ctile += __shfl_xor(ctile, 16, 64);
      ctile += __shfl_xor(ctile, 32, 64);
      if (quad == 0)
        Pc[(((size_t)J * NT + I) * 4 + wave) * TILE + t * 16 + lr] = ctile;
    }
  }

  // ---- row sums: reduce across the 16 lanes of each quad, store float4 ----
  #pragma unroll
  for (int m = 1; m < 16; m <<= 1)
    #pragma unroll
    for (int rt = 0; rt < 2; rt++)
      #pragma unroll
      for (int r = 0; r < 4; r++)
        rowsum[rt][r] += __shfl_xor(rowsum[rt][r], m, 64);
  if (lr == 0) {
    // lane (quad q) holds rows quad*4 + 0..3 of its rowtile: one float4 store
    float* Prow = P + ((size_t)I * NT + J) * TILE + wave * 32;
    #pragma unroll
    for (int rt = 0; rt < 2; rt++) {
      float4v v = {rowsum[rt][0], rowsum[rt][1], rowsum[rt][2], rowsum[rt][3]};
      *(float4v*)&Prow[rt * 16 + quad * 4] = v;
    }
  }
}

// ---------------------------------------------------------------------------
// Kernel 3: per-row reduction of P/Pc + log term + final sum (fused).
// 64 blocks x 128 threads, one thread per row r (row-tile X = blockIdx):
//   denom[r] = sum_{Y>=X} P[X][Y][rr] + sum_{Y<X} sum_w Pc[X][Y][w][rr]
//   term = (log(denom - e^2) - 2*pos[r mod B]) / N2   (double)
// Block double-reduce -> ONE float atomicAdd into out[0] (zeroed by norm).
// ---------------------------------------------------------------------------
__global__ __launch_bounds__(128) void reduce_rows(
    const float* __restrict__ P, const float* __restrict__ Pc,
    const float* __restrict__ pos, float* __restrict__ out) {
  __shared__ double sred[128];
  const int tid = threadIdx.x;
  const int r   = blockIdx.x * 128 + tid;       // 64*128 = 8192 rows
  const int X   = r >> 7;                       // uniform per block
  const int rr  = r & (TILE - 1);

  float acc = 0.0f;
  for (int Y = 0; Y < NT; Y++) {
    if (Y >= X) {
      acc += P[((size_t)X * NT + Y) * TILE + rr];
    } else {
      const float* pc = Pc + ((size_t)X * NT + Y) * 4 * TILE + rr;
      acc += pc[0] + pc[TILE] + pc[2 * TILE] + pc[3 * TILE];
    }
  }

  double term = (double)(logf(acc - DIAG_E2) - 2.0f * pos[r & (BB - 1)]) /
                (double)N2;
  sred[tid] = term;
  __syncthreads();
  #pragma unroll
  for (int s = 64; s; s >>= 1) {
    if (tid < s) sred[tid] += sred[tid + s];
    __syncthreads();
  }
  if (tid == 0) atomicAdd(out, (float)sred[0]);
}

// ---------------------------------------------------------------------------
extern "C" void kernel_launch(void* const* d_in, const int* in_sizes, int n_in,
                              void* d_out, int out_size, void* d_ws, size_t ws_size,
                              hipStream_t stream) {
  const float* emb_i = (const float*)d_in[0];
  const float* emb_j = (const float*)d_in[1];

  // workspace layout
  __hip_bfloat16* z = (__hip_bfloat16*)d_ws;                       // 2 MiB
  float* pos = (float*)((char*)d_ws + (size_t)N2 * DIMS * 2);      // 4096 f32
  float* P   = pos + BB;                                           // 2 MiB
  float* Pc  = P + (size_t)NT * NT * TILE;                         // 8 MiB

  norm_kernel<<<BB / 4, 256, 0, stream>>>(emb_i, emb_j, z, pos, (float*)d_out);
  simloss_sym<<<NJOBS, 256, 0, stream>>>(z, P, Pc);
  reduce_rows<<<NT, 128, 0, stream>>>(P, Pc, pos, (float*)d_out);
}

// Round 9
// 100.035 us; speedup vs baseline: 1.2031x; 1.2031x over previous
//
#include <hip/hip_runtime.h>
#include <hip/hip_bf16.h>
#include <math.h>

// Problem constants (B=4096, D=128, T=0.5 -> 1/T = 2)
#define BB       4096
#define N2       8192          // 2B rows of z
#define DIMS     128
#define NT       64            // number of 128-row tiles per matrix side
#define TILE     128
#define NPAIR    32            // panel pairs (I, 63-I)
#define SLOTS    16            // blocks per pair (slot strides J by 16)
#define NBLOCKS  (NPAIR * SLOTS)   // 512 persistent blocks, 2/CU
#define LDS_PAD  8             // bf16 pad per row: breaks 256B-stride conflicts
#define LDS_ROWW (DIMS + LDS_PAD)  // 136 shorts = 272 B

// z rows are pre-scaled by ZSCALE so the MFMA dot directly yields
// sim * 2*log2(e), i.e. exp(sim/T) = exp2(acc). ZSCALE^2 = 2.8853900818.
#define ZSCALE   1.6986436f
// diagonal term exp(2 * |z_r|^2) ~= exp(2) — subtracted in reduce.
#define DIAG_E2  7.38905609893065f

typedef __attribute__((ext_vector_type(8))) short short8;   // 8 x bf16 (4 VGPRs)
typedef __attribute__((ext_vector_type(4))) float float4v;  // MFMA C/D

// ---------------------------------------------------------------------------
// Kernel 1: normalize rows (fp32), compute positives (fp32), write z as
// bf16 scaled by ZSCALE. Zeroes out[0]. One wave per row-pair r.
// (r7 lesson: normalize exactly once.)
// ---------------------------------------------------------------------------
__global__ __launch_bounds__(256) void norm_kernel(
    const float* __restrict__ emb_i, const float* __restrict__ emb_j,
    __hip_bfloat16* __restrict__ z, float* __restrict__ pos,
    float* __restrict__ out) {
  if (blockIdx.x == 0 && threadIdx.x == 0) out[0] = 0.0f;

  int gw   = (blockIdx.x * blockDim.x + threadIdx.x) >> 6;  // row pair
  int lane = threadIdx.x & 63;
  if (gw >= BB) return;

  const float2* ei = (const float2*)(emb_i + (size_t)gw * DIMS);
  const float2* ej = (const float2*)(emb_j + (size_t)gw * DIMS);
  float2 a = ei[lane];
  float2 b = ej[lane];

  float sa = a.x * a.x + a.y * a.y;
  float sb = b.x * b.x + b.y * b.y;
  #pragma unroll
  for (int m = 32; m; m >>= 1) {
    sa += __shfl_xor(sa, m, 64);
    sb += __shfl_xor(sb, m, 64);
  }
  float inva = 1.0f / fmaxf(sqrtf(sa), 1e-12f);
  float invb = 1.0f / fmaxf(sqrtf(sb), 1e-12f);

  float zi0 = a.x * inva, zi1 = a.y * inva;
  float zj0 = b.x * invb, zj1 = b.y * invb;

  float p = zi0 * zj0 + zi1 * zj1;
  #pragma unroll
  for (int m = 32; m; m >>= 1) p += __shfl_xor(p, m, 64);
  if (lane == 0) pos[gw] = p;

  __hip_bfloat162* zr_i = (__hip_bfloat162*)(z + (size_t)gw * DIMS);
  __hip_bfloat162* zr_j = (__hip_bfloat162*)(z + (size_t)(gw + BB) * DIMS);
  __hip_bfloat162 vi, vj;
  vi.x = __float2bfloat16(zi0 * ZSCALE); vi.y = __float2bfloat16(zi1 * ZSCALE);
  vj.x = __float2bfloat16(zj0 * ZSCALE); vj.y = __float2bfloat16(zj1 * ZSCALE);
  zr_i[lane] = vi;
  zr_j[lane] = vj;
}

// ---------------------------------------------------------------------------
// Kernel 2: PERSISTENT symmetric sim-GEMM + exp2, software-pipelined jobs.
// r4-r8 invariant: every per-job-dispatch variant sits at 25-47 µs with all
// pipes <30% — the un-overlapped per-job stage->wait->compute chain is the
// bottleneck. Here 512 co-resident blocks (2/CU) each own panel pair
// (I=p, 63-p), slot s takes J = Ip+s, Ip+s+16, ... (4-5 jobs/block):
//  * A-frags loaded ONCE per phase; row-sums live in registers across all
//    jobs of the phase, stored once to P[Ip][s][:] (no per-job epilogue);
//  * per job: issue next B-tile's global loads -> t-loop on lds[cur] ->
//    ds_write next tile to lds[cur^1] -> ONE barrier (T14 split: next
//    tile's HBM/L2 latency hides under the current ~1250-cycle t-loop);
//  * col-partials: wave-private Pc[J][Ip][wave][:] stores (no atomics).
// Staging addresses identical to r6 -> bit-identical MFMA inputs.
// ---------------------------------------------------------------------------
__global__ __launch_bounds__(256, 2) void simloss_persist(
    const __hip_bfloat16* __restrict__ z, float* __restrict__ P,
    float* __restrict__ Pc) {
  __shared__ short lds[2][TILE * LDS_ROWW];   // 2 x 34816 B = 69632 B

  const int tid  = threadIdx.x;
  const int wave = tid >> 6;
  const int lane = tid & 63;
  const int lr   = lane & 15;          // A-row / B-col / C-col within tile
  const int quad = lane >> 4;          // k-group for A/B, row-group for C
  const int p    = blockIdx.x >> 4;    // pair 0..31
  const int s    = blockIdx.x & 15;    // slot 0..15

  const ushort* zp = (const ushort*)z;

  #pragma unroll
  for (int phase = 0; phase < 2; ++phase) {
    const int Ip = phase ? (NT - 1 - p) : p;
    const int R0 = Ip * TILE;

    // ---- A fragments for this panel (loaded once per phase) ----
    short8 afrag[2][4];
    #pragma unroll
    for (int rt = 0; rt < 2; rt++) {
      const int arow = R0 + wave * 32 + rt * 16 + lr;
      const short8* ap = (const short8*)(zp + (size_t)arow * DIMS + quad * 8);
      afrag[rt][0] = ap[0];
      afrag[rt][1] = ap[4];
      afrag[rt][2] = ap[8];
      afrag[rt][3] = ap[12];
    }

    float rowsum[2][4];
    #pragma unroll
    for (int rt = 0; rt < 2; rt++)
      #pragma unroll
      for (int r = 0; r < 4; r++) rowsum[rt][r] = 0.0f;

    const int J0 = Ip + s;
    short8 stg[8];

    // ---- prologue: stage first B-tile into lds[0] ----
    if (J0 < NT) {
      const short8* src = (const short8*)(zp + (size_t)J0 * TILE * DIMS);
      #pragma unroll
      for (int i = 0; i < 8; i++) stg[i] = src[tid + 256 * i];
      #pragma unroll
      for (int i = 0; i < 8; i++) {
        int idx = tid + 256 * i;
        int row = idx >> 4;
        int col8 = idx & 15;
        *(short8*)&lds[0][row * LDS_ROWW + col8 * 8] = stg[i];
      }
    }
    __syncthreads();                   // J0 is block-uniform: no divergence

    int cur = 0;
    for (int J = J0; J < NT; J += SLOTS) {
      const int Jn = J + SLOTS;
      // ---- issue next tile's global loads EARLY (hide under t-loop) ----
      if (Jn < NT) {
        const short8* src = (const short8*)(zp + (size_t)Jn * TILE * DIMS);
        #pragma unroll
        for (int i = 0; i < 8; i++) stg[i] = src[tid + 256 * i];
      }

      const bool diag = (J == Ip);
      // ---- t-loop on lds[cur] (verified r6 core) ----
      #pragma unroll 2
      for (int t = 0; t < 8; t++) {
        const short8* bp =
            (const short8*)&lds[cur][(t * 16 + lr) * LDS_ROWW + quad * 8];
        short8 b0 = bp[0];
        short8 b1 = bp[4];
        short8 b2 = bp[8];
        short8 b3 = bp[12];
        float ctile = 0.0f;
        #pragma unroll
        for (int rt = 0; rt < 2; rt++) {
          float4v acc = {0.0f, 0.0f, 0.0f, 0.0f};
          acc = __builtin_amdgcn_mfma_f32_16x16x32_bf16(afrag[rt][0], b0, acc, 0, 0, 0);
          acc = __builtin_amdgcn_mfma_f32_16x16x32_bf16(afrag[rt][1], b1, acc, 0, 0, 0);
          acc = __builtin_amdgcn_mfma_f32_16x16x32_bf16(afrag[rt][2], b2, acc, 0, 0, 0);
          acc = __builtin_amdgcn_mfma_f32_16x16x32_bf16(afrag[rt][3], b3, acc, 0, 0, 0);
          // exp(sim/T) = exp2(acc) thanks to ZSCALE pre-scaling.
          #pragma unroll
          for (int r = 0; r < 4; r++) {
            float e = __builtin_amdgcn_exp2f(acc[r]);
            rowsum[rt][r] += e;
            ctile += e;
          }
        }
        if (!diag) {  // block-uniform branch
          // col sums over this wave's 32 rows
          ctile += __shfl_xor(ctile, 16, 64);
          ctile += __shfl_xor(ctile, 32, 64);
          if (quad == 0)
            Pc[(((size_t)J * NT + Ip) * 4 + wave) * TILE + t * 16 + lr] = ctile;
        }
      }

      // ---- write next tile into the other buffer, then one barrier ----
      if (Jn < NT) {
        #pragma unroll
        for (int i = 0; i < 8; i++) {
          int idx = tid + 256 * i;
          int row = idx >> 4;
          int col8 = idx & 15;
          *(short8*)&lds[cur ^ 1][row * LDS_ROWW + col8 * 8] = stg[i];
        }
      }
      __syncthreads();
      cur ^= 1;
    }

    // ---- phase epilogue: reduce rowsum across 16 lanes, store once ----
    #pragma unroll
    for (int m = 1; m < 16; m <<= 1)
      #pragma unroll
      for (int rt = 0; rt < 2; rt++)
        #pragma unroll
        for (int r = 0; r < 4; r++)
          rowsum[rt][r] += __shfl_xor(rowsum[rt][r], m, 64);
    if (lr == 0) {
      // quad q holds rows quad*4 + 0..3 of its rowtile
      float* Prow = P + ((size_t)Ip * SLOTS + s) * TILE + wave * 32;
      #pragma unroll
      for (int rt = 0; rt < 2; rt++) {
        float4v v = {rowsum[rt][0], rowsum[rt][1], rowsum[rt][2], rowsum[rt][3]};
        *(float4v*)&Prow[rt * 16 + quad * 4] = v;
      }
    }
    // no barrier needed here: phase-1 prologue writes lds[0], and all reads
    // of lds finished at the job loop's final barrier.
  }
}

// ---------------------------------------------------------------------------
// Kernel 3: per-row reduction of P/Pc + log term + final sum.
// 64 blocks x 128 threads, one thread per row r (row-tile X uniform/block):
//   denom[r] = sum_{s} P[X][s][rr] + sum_{Y<X} sum_w Pc[X][Y][w][rr]
//   term = (log(denom - e^2) - 2*pos[r mod B]) / N2   (double)
// Block double-reduce -> ONE float atomicAdd into out[0] (zeroed by norm).
// ---------------------------------------------------------------------------
__global__ __launch_bounds__(128) void reduce_rows(
    const float* __restrict__ P, const float* __restrict__ Pc,
    const float* __restrict__ pos, float* __restrict__ out) {
  __shared__ double sred[128];
  const int tid = threadIdx.x;
  const int r   = blockIdx.x * 128 + tid;       // 64*128 = 8192 rows
  const int X   = r >> 7;                       // uniform per block
  const int rr  = r & (TILE - 1);

  float acc = 0.0f;
  const float* pp = P + (size_t)X * SLOTS * TILE + rr;
  #pragma unroll
  for (int s2 = 0; s2 < SLOTS; s2++) acc += pp[(size_t)s2 * TILE];

  for (int Y = 0; Y < X; Y++) {
    const float* pc = Pc + ((size_t)X * NT + Y) * 4 * TILE + rr;
    acc += pc[0] + pc[TILE] + pc[2 * TILE] + pc[3 * TILE];
  }

  double term = (double)(logf(acc - DIAG_E2) - 2.0f * pos[r & (BB - 1)]) /
                (double)N2;
  sred[tid] = term;
  __syncthreads();
  #pragma unroll
  for (int s2 = 64; s2; s2 >>= 1) {
    if (tid < s2) sred[tid] += sred[tid + s2];
    __syncthreads();
  }
  if (tid == 0) atomicAdd(out, (float)sred[0]);
}

// ---------------------------------------------------------------------------
extern "C" void kernel_launch(void* const* d_in, const int* in_sizes, int n_in,
                              void* d_out, int out_size, void* d_ws, size_t ws_size,
                              hipStream_t stream) {
  const float* emb_i = (const float*)d_in[0];
  const float* emb_j = (const float*)d_in[1];

  // workspace layout
  __hip_bfloat16* z = (__hip_bfloat16*)d_ws;                       // 2 MiB
  float* pos = (float*)((char*)d_ws + (size_t)N2 * DIMS * 2);      // 4096 f32
  float* P   = pos + BB;                                           // 64*16*128 f32 = 512 KiB
  float* Pc  = P + (size_t)NT * SLOTS * TILE;                      // 8 MiB (lower-tri used)

  norm_kernel<<<BB / 4, 256, 0, stream>>>(emb_i, emb_j, z, pos, (float*)d_out);
  simloss_persist<<<NBLOCKS, 256, 0, stream>>>(z, P, Pc);
  reduce_rows<<<NT, 128, 0, stream>>>(P, Pc, pos, (float*)d_out);
}

// Round 10
// 84.482 us; speedup vs baseline: 1.4246x; 1.1841x over previous
//
#include <hip/hip_runtime.h>
#include <hip/hip_bf16.h>
#include <math.h>

// Problem constants (B=4096, D=128, T=0.5 -> 1/T = 2)
#define BB       4096
#define N2       8192          // 2B rows of z
#define DIMS     128
#define NT       64            // number of 128-row tiles per matrix side
#define NJOBS    (NT * (NT + 1) / 2)   // 2080 upper-triangle tile jobs
#define TILE     128

// z rows are pre-scaled by ZSCALE so the MFMA dot directly yields
// sim * 2*log2(e), i.e. exp(sim/T) = exp2(acc). ZSCALE^2 = 2.8853900818.
#define ZSCALE   1.6986436f
// diagonal term exp(2 * |z_r|^2) ~= exp(2) — subtracted in reduce.
#define DIAG_E2  7.38905609893065f

typedef __attribute__((ext_vector_type(8))) short short8;   // 8 x bf16 (4 VGPRs)
typedef __attribute__((ext_vector_type(4))) float float4v;  // MFMA C/D

// ---------------------------------------------------------------------------
// Kernel 1: normalize rows (fp32), compute positives (fp32), write z as
// bf16 scaled by ZSCALE. Zeroes out[0] (reduce accumulates into it).
// One wave per row-pair r: emb_i[r] -> z[r], emb_j[r] -> z[r+B].
// (r7 lesson: normalize exactly once.)
// ---------------------------------------------------------------------------
__global__ __launch_bounds__(256) void norm_kernel(
    const float* __restrict__ emb_i, const float* __restrict__ emb_j,
    __hip_bfloat16* __restrict__ z, float* __restrict__ pos,
    float* __restrict__ out) {
  if (blockIdx.x == 0 && threadIdx.x == 0) out[0] = 0.0f;

  int gw   = (blockIdx.x * blockDim.x + threadIdx.x) >> 6;  // row pair
  int lane = threadIdx.x & 63;
  if (gw >= BB) return;

  const float2* ei = (const float2*)(emb_i + (size_t)gw * DIMS);
  const float2* ej = (const float2*)(emb_j + (size_t)gw * DIMS);
  float2 a = ei[lane];
  float2 b = ej[lane];

  float sa = a.x * a.x + a.y * a.y;
  float sb = b.x * b.x + b.y * b.y;
  #pragma unroll
  for (int m = 32; m; m >>= 1) {
    sa += __shfl_xor(sa, m, 64);
    sb += __shfl_xor(sb, m, 64);
  }
  float inva = 1.0f / fmaxf(sqrtf(sa), 1e-12f);
  float invb = 1.0f / fmaxf(sqrtf(sb), 1e-12f);

  float zi0 = a.x * inva, zi1 = a.y * inva;
  float zj0 = b.x * invb, zj1 = b.y * invb;

  // positive pair dot in unscaled fp32 (matches reference's fp32 einsum)
  float p = zi0 * zj0 + zi1 * zj1;
  #pragma unroll
  for (int m = 32; m; m >>= 1) p += __shfl_xor(p, m, 64);
  if (lane == 0) pos[gw] = p;

  __hip_bfloat162* zr_i = (__hip_bfloat162*)(z + (size_t)gw * DIMS);
  __hip_bfloat162* zr_j = (__hip_bfloat162*)(z + (size_t)(gw + BB) * DIMS);
  __hip_bfloat162 vi, vj;
  vi.x = __float2bfloat16(zi0 * ZSCALE); vi.y = __float2bfloat16(zi1 * ZSCALE);
  vj.x = __float2bfloat16(zj0 * ZSCALE); vj.y = __float2bfloat16(zj1 * ZSCALE);
  zr_i[lane] = vi;
  zr_j[lane] = vj;
}

// ---------------------------------------------------------------------------
// Kernel 2: symmetric sim-GEMM + exp2 -> private partials. EXACT r6 structure
// (best measured: 82.3 µs total) with ONE change: B-staging via async
// global_load_lds width=16 issued BEFORE the A-frag loads, so the B-tile DMA
// overlaps A-frag latency and the barrier's single vmcnt drain synchronizes.
//  * LDS layout is LINEAR (global_load_lds writes wave-uniform base+lane*16);
//    bank conflicts handled by BOTH-SIDES XOR swizzle (rule #21):
//    inverse-swizzled global SOURCE + swizzled ds_read, byte ^= ((row&7)<<4).
//    Read pattern: 8 lanes per 4-bank group = conflict-free b128 floor.
//  * MFMA inputs are bit-identical to r6 (same logical elements).
// Block (I,J), I<J writes row-partials to P[I][J][:] and col-partials to
// P[J][I][:]; diag writes P[I][I][:]. Every cell written exactly once, no
// atomics, no fences (r1/r3 post-mortems).
// ---------------------------------------------------------------------------
__global__ __launch_bounds__(256, 4) void simloss_sym(
    const __hip_bfloat16* __restrict__ z, float* __restrict__ P) {
  __shared__ short lds[TILE * DIMS];       // 128 x 128 bf16 LINEAR = 32768 B
  __shared__ float csum_lds[4][TILE];      // per-wave column-sum partials

  const int tid  = threadIdx.x;
  const int wave = tid >> 6;
  const int lane = tid & 63;
  const int lr   = lane & 15;          // A-row / B-col / C-col within tile
  const int quad = lane >> 4;          // k-group for A/B, row-group for C

  // ---- decode flat job id -> (I, J) with I <= J over NT=64 ----
  const int j = blockIdx.x;
  int I = (int)((129.0f - sqrtf(16641.0f - 8.0f * (float)j)) * 0.5f);
  I = I < 0 ? 0 : (I > NT - 1 ? NT - 1 : I);
  while (I < NT - 1 && (I + 1) * (2 * NT - I) / 2 <= j) ++I;
  while (I > 0 && I * (2 * NT - I + 1) / 2 > j) --I;
  const int J = I + (j - I * (2 * NT - I + 1) / 2);
  const bool diag = (I == J);
  const int R0 = I * TILE;
  const int C0 = J * TILE;

  const ushort* zp = (const ushort*)z;

  // ---- B stage FIRST: async global->LDS, 8 x 1KB per wave ----
  // LDS dest is linear; global source is inverse-XOR-swizzled so that the
  // swizzled ds_read below recovers the logical element (involution).
  {
    const char* srcb = (const char*)(zp + (size_t)C0 * DIMS);
    char* ldsb = (char*)lds;
    #pragma unroll
    for (int i = 0; i < 8; i++) {
      const int lin = (wave * 8 + i) * 1024 + lane * 16;  // byte offset
      const int sw  = ((lin >> 8) & 7) << 4;              // row&7 (row=lin>>8)
      __builtin_amdgcn_global_load_lds(
          (const __attribute__((address_space(1))) void*)(srcb + (lin ^ sw)),
          (__attribute__((address_space(3))) void*)(ldsb + (wave * 8 + i) * 1024),
          16, 0, 0);
    }
  }

  // ---- A fragments pinned in VGPRs: rows R0 + wave*32 + rt*16 + lr ----
  // (flat loads; their waitcnt folds into first MFMA use, overlapping above)
  short8 afrag[2][4];
  #pragma unroll
  for (int rt = 0; rt < 2; rt++) {
    const int arow = R0 + wave * 32 + rt * 16 + lr;
    const short8* ap = (const short8*)(zp + (size_t)arow * DIMS + quad * 8);
    afrag[rt][0] = ap[0];
    afrag[rt][1] = ap[4];   // +32 shorts
    afrag[rt][2] = ap[8];
    afrag[rt][3] = ap[12];
  }

  __syncthreads();   // drains vmcnt(0): B tile resident in LDS

  float rowsum[2][4];
  #pragma unroll
  for (int rt = 0; rt < 2; rt++)
    #pragma unroll
    for (int r = 0; r < 4; r++) rowsum[rt][r] = 0.0f;

  #pragma unroll 2
  for (int t = 0; t < 8; t++) {        // 8 column tiles of 16
    const int row  = t * 16 + lr;
    const int base = row * 256 + quad * 16;   // byte addr of logical frag
    const int sw   = (row & 7) << 4;
    const char* lb = (const char*)lds;
    short8 b0 = *(const short8*)(lb + ((base      ) ^ sw));
    short8 b1 = *(const short8*)(lb + ((base +  64) ^ sw));
    short8 b2 = *(const short8*)(lb + ((base + 128) ^ sw));
    short8 b3 = *(const short8*)(lb + ((base + 192) ^ sw));
    float ctile = 0.0f;
    #pragma unroll
    for (int rt = 0; rt < 2; rt++) {
      float4v acc = {0.0f, 0.0f, 0.0f, 0.0f};
      acc = __builtin_amdgcn_mfma_f32_16x16x32_bf16(afrag[rt][0], b0, acc, 0, 0, 0);
      acc = __builtin_amdgcn_mfma_f32_16x16x32_bf16(afrag[rt][1], b1, acc, 0, 0, 0);
      acc = __builtin_amdgcn_mfma_f32_16x16x32_bf16(afrag[rt][2], b2, acc, 0, 0, 0);
      acc = __builtin_amdgcn_mfma_f32_16x16x32_bf16(afrag[rt][3], b3, acc, 0, 0, 0);
      // exp(sim/T) = exp2(acc) thanks to ZSCALE pre-scaling.
      #pragma unroll
      for (int r = 0; r < 4; r++) {
        float e = __builtin_amdgcn_exp2f(acc[r]);
        rowsum[rt][r] += e;
        ctile += e;
      }
    }
    if (!diag) {  // block-uniform branch
      // column sums: reduce over the wave's 32 rows (4 regs above, now quads)
      ctile += __shfl_xor(ctile, 16, 64);
      ctile += __shfl_xor(ctile, 32, 64);
      if (quad == 0) csum_lds[wave][t * 16 + lr] = ctile;
    }
  }

  // ---- row sums: reduce across the 16 lanes of each quad, store float4 ----
  #pragma unroll
  for (int m = 1; m < 16; m <<= 1)
    #pragma unroll
    for (int rt = 0; rt < 2; rt++)
      #pragma unroll
      for (int r = 0; r < 4; r++)
        rowsum[rt][r] += __shfl_xor(rowsum[rt][r], m, 64);
  if (lr == 0) {
    // lane (quad q) holds rows quad*4 + 0..3 of its rowtile: one float4 store
    float* Prow = P + ((size_t)I * NT + J) * TILE + wave * 32;
    #pragma unroll
    for (int rt = 0; rt < 2; rt++) {
      float4v v = {rowsum[rt][0], rowsum[rt][1], rowsum[rt][2], rowsum[rt][3]};
      *(float4v*)&Prow[rt * 16 + quad * 4] = v;
    }
  }

  // ---- column sums: combine 4 wave partials, coalesced store ----
  if (!diag) {
    __syncthreads();
    if (tid < TILE) {
      float s = csum_lds[0][tid] + csum_lds[1][tid] +
                csum_lds[2][tid] + csum_lds[3][tid];
      P[((size_t)J * NT + I) * TILE + tid] = s;
    }
  }
}

// ---------------------------------------------------------------------------
// Kernel 3: per-row reduction of P + log term + final sum (fused).
// 64 blocks x 128 threads, one thread per row r:
//   denom[r] = sum_J P[r>>7][J][r&127] (fp32, fixed order)
//   term = (log(denom - e^2) - 2*pos[r mod B]) / N2   (double)
// Block double-reduce -> ONE float atomicAdd into out[0] (zeroed by norm).
// ---------------------------------------------------------------------------
__global__ __launch_bounds__(128) void reduce_rows(
    const float* __restrict__ P, const float* __restrict__ pos,
    float* __restrict__ out) {
  __shared__ double sred[128];
  const int tid = threadIdx.x;
  const int r   = blockIdx.x * 128 + tid;       // 64*128 = 8192 rows
  const int I   = r >> 7;
  const int rr  = r & (TILE - 1);

  const float* p = P + (size_t)I * NT * TILE + rr;
  float acc = 0.0f;
  #pragma unroll 8
  for (int J = 0; J < NT; J++) acc += p[(size_t)J * TILE];

  double term = (double)(logf(acc - DIAG_E2) - 2.0f * pos[r & (BB - 1)]) /
                (double)N2;
  sred[tid] = term;
  __syncthreads();
  #pragma unroll
  for (int s = 64; s; s >>= 1) {
    if (tid < s) sred[tid] += sred[tid + s];
    __syncthreads();
  }
  if (tid == 0) atomicAdd(out, (float)sred[0]);
}

// ---------------------------------------------------------------------------
extern "C" void kernel_launch(void* const* d_in, const int* in_sizes, int n_in,
                              void* d_out, int out_size, void* d_ws, size_t ws_size,
                              hipStream_t stream) {
  const float* emb_i = (const float*)d_in[0];
  const float* emb_j = (const float*)d_in[1];

  // workspace layout
  __hip_bfloat16* z = (__hip_bfloat16*)d_ws;                       // 2 MiB
  float* pos = (float*)((char*)d_ws + (size_t)N2 * DIMS * 2);      // 4096 f32
  float* P   = pos + BB;                                           // 2 MiB

  norm_kernel<<<BB / 4, 256, 0, stream>>>(emb_i, emb_j, z, pos, (float*)d_out);
  simloss_sym<<<NJOBS, 256, 0, stream>>>(z, P);
  reduce_rows<<<N2 / 128, 128, 0, stream>>>(P, pos, (float*)d_out);
}

// Round 11
// 81.023 us; speedup vs baseline: 1.4855x; 1.0427x over previous
//
#include <hip/hip_runtime.h>
#include <hip/hip_bf16.h>
#include <math.h>

// Problem constants (B=4096, D=128, T=0.5 -> 1/T = 2)
#define BB       4096
#define N2       8192          // 2B rows of z
#define DIMS     128
#define NT       64            // number of 128-row tiles per matrix side
#define NJOBS    (NT * (NT + 1) / 2)   // 2080 upper-triangle tile jobs
#define TILE     128
#define LDS_PAD  8             // bf16 pad per row: breaks 256B-stride 16B-group conflicts
#define LDS_ROWW (DIMS + LDS_PAD)  // 136 shorts = 272 B

// z rows are pre-scaled by ZSCALE so the MFMA dot directly yields
// sim * 2*log2(e), i.e. exp(sim/T) = exp2(acc). ZSCALE^2 = 2.8853900818.
#define ZSCALE   1.6986436f
// diagonal term exp(2 * |z_r|^2) ~= exp(2) — subtracted in reduce.
#define DIAG_E2  7.38905609893065f

typedef __attribute__((ext_vector_type(8))) short short8;   // 8 x bf16 (4 VGPRs)
typedef __attribute__((ext_vector_type(4))) float float4v;  // MFMA C/D

// ---------------------------------------------------------------------------
// Kernel 1: normalize rows (fp32), compute positives (fp32), write z as
// bf16 scaled by ZSCALE. Also zeroes out[0] (accumulated by reduce_rows via
// float atomics; stream order + kernel boundary make the zero visible).
// One wave per row-pair r: emb_i[r] -> z[r], emb_j[r] -> z[r+B].
// ---------------------------------------------------------------------------
__global__ __launch_bounds__(256) void norm_kernel(
    const float* __restrict__ emb_i, const float* __restrict__ emb_j,
    __hip_bfloat16* __restrict__ z, float* __restrict__ pos,
    float* __restrict__ out) {
  if (blockIdx.x == 0 && threadIdx.x == 0) out[0] = 0.0f;

  int gw   = (blockIdx.x * blockDim.x + threadIdx.x) >> 6;  // row pair
  int lane = threadIdx.x & 63;
  if (gw >= BB) return;

  const float2* ei = (const float2*)(emb_i + (size_t)gw * DIMS);
  const float2* ej = (const float2*)(emb_j + (size_t)gw * DIMS);
  float2 a = ei[lane];
  float2 b = ej[lane];

  float sa = a.x * a.x + a.y * a.y;
  float sb = b.x * b.x + b.y * b.y;
  #pragma unroll
  for (int m = 32; m; m >>= 1) {
    sa += __shfl_xor(sa, m, 64);
    sb += __shfl_xor(sb, m, 64);
  }
  float inva = 1.0f / fmaxf(sqrtf(sa), 1e-12f);
  float invb = 1.0f / fmaxf(sqrtf(sb), 1e-12f);

  float zi0 = a.x * inva, zi1 = a.y * inva;
  float zj0 = b.x * invb, zj1 = b.y * invb;

  // positive pair dot in unscaled fp32 (matches reference's fp32 einsum)
  float p = zi0 * zj0 + zi1 * zj1;
  #pragma unroll
  for (int m = 32; m; m >>= 1) p += __shfl_xor(p, m, 64);
  if (lane == 0) pos[gw] = p;

  __hip_bfloat162* zr_i = (__hip_bfloat162*)(z + (size_t)gw * DIMS);
  __hip_bfloat162* zr_j = (__hip_bfloat162*)(z + (size_t)(gw + BB) * DIMS);
  __hip_bfloat162 vi, vj;
  vi.x = __float2bfloat16(zi0 * ZSCALE); vi.y = __float2bfloat16(zi1 * ZSCALE);
  vj.x = __float2bfloat16(zj0 * ZSCALE); vj.y = __float2bfloat16(zj1 * ZSCALE);
  zr_i[lane] = vi;
  zr_j[lane] = vj;
}

// ---------------------------------------------------------------------------
// Kernel 2: symmetric fused sim-GEMM + exp2 -> PRIVATE partials (no atomics).
// BYTE-IDENTICAL to the round-6 version (best measured configuration:
// 82.3 µs total). Ten structural variants (r0-r10) bracket this as the local
// optimum: atomics removal (+8.5) and kernel-count reduction (+1.5) helped;
// fused-norm (-18), no-LDS (-38), persistent-pipelined (-18), and async
// global_load_lds staging (-2) all regressed or were neutral.
// Block (I,J), I<J writes row-partials to P[I][J][:] and col-partials to
// P[J][I][:]; diag writes P[I][I][:]. Every cell written exactly once.
// MFMA dot is bit-identical under operand transpose, so symmetry is exact.
// ---------------------------------------------------------------------------
__global__ __launch_bounds__(256, 4) void simloss_sym(
    const __hip_bfloat16* __restrict__ z, float* __restrict__ P) {
  __shared__ short lds[TILE * LDS_ROWW];   // 128 x 136 bf16 = 34816 B
  __shared__ float csum_lds[4][TILE];      // per-wave column-sum partials

  const int tid  = threadIdx.x;
  const int wave = tid >> 6;
  const int lane = tid & 63;
  const int lr   = lane & 15;          // A-row / B-col / C-col within tile
  const int quad = lane >> 4;          // k-group for A/B, row-group for C

  // ---- decode flat job id -> (I, J) with I <= J over NT=64 ----
  // base(I) = I*(2*NT - I + 1)/2 ; float guess + integer fixup.
  const int j = blockIdx.x;
  int I = (int)((129.0f - sqrtf(16641.0f - 8.0f * (float)j)) * 0.5f);
  I = I < 0 ? 0 : (I > NT - 1 ? NT - 1 : I);
  while (I < NT - 1 && (I + 1) * (2 * NT - I) / 2 <= j) ++I;
  while (I > 0 && I * (2 * NT - I + 1) / 2 > j) --I;
  const int J = I + (j - I * (2 * NT - I + 1) / 2);
  const bool diag = (I == J);
  const int R0 = I * TILE;
  const int C0 = J * TILE;

  const ushort* zp = (const ushort*)z;

  // ---- A fragments pinned in VGPRs: rows R0 + wave*32 + rt*16 + lr ----
  short8 afrag[2][4];
  #pragma unroll
  for (int rt = 0; rt < 2; rt++) {
    const int arow = R0 + wave * 32 + rt * 16 + lr;
    const short8* ap = (const short8*)(zp + (size_t)arow * DIMS + quad * 8);
    afrag[rt][0] = ap[0];
    afrag[rt][1] = ap[4];   // +32 shorts
    afrag[rt][2] = ap[8];
    afrag[rt][3] = ap[12];
  }

  // ---- stage B tile: 128 cols x 128 dims (2048 short8, 8 per thread) ----
  {
    const short8* src = (const short8*)(zp + (size_t)C0 * DIMS);
    #pragma unroll
    for (int i = 0; i < 8; i++) {
      int idx  = tid + 256 * i;
      int row  = idx >> 4;             // 16 short8 per logical row
      int col8 = idx & 15;
      *(short8*)&lds[row * LDS_ROWW + col8 * 8] = src[idx];
    }
  }
  __syncthreads();

  float rowsum[2][4];
  #pragma unroll
  for (int rt = 0; rt < 2; rt++)
    #pragma unroll
    for (int r = 0; r < 4; r++) rowsum[rt][r] = 0.0f;

  #pragma unroll 2
  for (int t = 0; t < 8; t++) {        // 8 column tiles of 16
    const short8* bp = (const short8*)&lds[(t * 16 + lr) * LDS_ROWW + quad * 8];
    short8 b0 = bp[0];
    short8 b1 = bp[4];
    short8 b2 = bp[8];
    short8 b3 = bp[12];
    float ctile = 0.0f;
    #pragma unroll
    for (int rt = 0; rt < 2; rt++) {
      float4v acc = {0.0f, 0.0f, 0.0f, 0.0f};
      acc = __builtin_amdgcn_mfma_f32_16x16x32_bf16(afrag[rt][0], b0, acc, 0, 0, 0);
      acc = __builtin_amdgcn_mfma_f32_16x16x32_bf16(afrag[rt][1], b1, acc, 0, 0, 0);
      acc = __builtin_amdgcn_mfma_f32_16x16x32_bf16(afrag[rt][2], b2, acc, 0, 0, 0);
      acc = __builtin_amdgcn_mfma_f32_16x16x32_bf16(afrag[rt][3], b3, acc, 0, 0, 0);
      // exp(sim/T) = exp2(acc) thanks to ZSCALE pre-scaling.
      #pragma unroll
      for (int r = 0; r < 4; r++) {
        float e = __builtin_amdgcn_exp2f(acc[r]);
        rowsum[rt][r] += e;
        ctile += e;
      }
    }
    if (!diag) {  // block-uniform branch
      // column sums: reduce over the wave's 32 rows (4 regs done above, now quads)
      ctile += __shfl_xor(ctile, 16, 64);
      ctile += __shfl_xor(ctile, 32, 64);
      if (quad == 0) csum_lds[wave][t * 16 + lr] = ctile;
    }
  }

  // ---- row sums: reduce across the 16 lanes of each quad, store float4 ----
  #pragma unroll
  for (int m = 1; m < 16; m <<= 1)
    #pragma unroll
    for (int rt = 0; rt < 2; rt++)
      #pragma unroll
      for (int r = 0; r < 4; r++)
        rowsum[rt][r] += __shfl_xor(rowsum[rt][r], m, 64);
  if (lr == 0) {
    // lane (quad q) holds rows quad*4 + 0..3 of its rowtile: one float4 store
    float* Prow = P + ((size_t)I * NT + J) * TILE + wave * 32;
    #pragma unroll
    for (int rt = 0; rt < 2; rt++) {
      float4v v = {rowsum[rt][0], rowsum[rt][1], rowsum[rt][2], rowsum[rt][3]};
      *(float4v*)&Prow[rt * 16 + quad * 4] = v;
    }
  }

  // ---- column sums: combine 4 wave partials, coalesced store ----
  if (!diag) {
    __syncthreads();
    if (tid < TILE) {
      float s = csum_lds[0][tid] + csum_lds[1][tid] +
                csum_lds[2][tid] + csum_lds[3][tid];
      P[((size_t)J * NT + I) * TILE + tid] = s;
    }
  }
}

// ---------------------------------------------------------------------------
// Kernel 3: per-row reduction of P + log term + final sum (fused).
// 64 blocks x 128 threads, one thread per row r:
//   denom[r] = sum_J P[r>>7][J][r&127] (fp32, fixed order)
//   term = (log(denom - e^2) - 2*pos[r mod B]) / N2   (double)
// Block double-reduce -> ONE float atomicAdd into out[0] (zeroed by norm).
// 64 float adds of ~0.16 into ~10: error ~3e-5, far inside tolerance.
// ---------------------------------------------------------------------------
__global__ __launch_bounds__(128) void reduce_rows(
    const float* __restrict__ P, const float* __restrict__ pos,
    float* __restrict__ out) {
  __shared__ double sred[128];
  const int tid = threadIdx.x;
  const int r   = blockIdx.x * 128 + tid;       // 64*128 = 8192 rows
  const int I   = r >> 7;
  const int rr  = r & (TILE - 1);

  const float* p = P + (size_t)I * NT * TILE + rr;
  float acc = 0.0f;
  #pragma unroll 8
  for (int J = 0; J < NT; J++) acc += p[(size_t)J * TILE];

  double term = (double)(logf(acc - DIAG_E2) - 2.0f * pos[r & (BB - 1)]) /
                (double)N2;
  sred[tid] = term;
  __syncthreads();
  #pragma unroll
  for (int s = 64; s; s >>= 1) {
    if (tid < s) sred[tid] += sred[tid + s];
    __syncthreads();
  }
  if (tid == 0) atomicAdd(out, (float)sred[0]);
}

// ---------------------------------------------------------------------------
extern "C" void kernel_launch(void* const* d_in, const int* in_sizes, int n_in,
                              void* d_out, int out_size, void* d_ws, size_t ws_size,
                              hipStream_t stream) {
  const float* emb_i = (const float*)d_in[0];
  const float* emb_j = (const float*)d_in[1];

  // workspace layout
  __hip_bfloat16* z = (__hip_bfloat16*)d_ws;                       // 2 MiB
  float* pos = (float*)((char*)d_ws + (size_t)N2 * DIMS * 2);      // 4096 f32
  float* P   = pos + BB;                                           // 64*64*128 f32 = 2 MiB

  norm_kernel<<<BB / 4, 256, 0, stream>>>(emb_i, emb_j, z, pos, (float*)d_out);
  simloss_sym<<<NJOBS, 256, 0, stream>>>(z, P);
  reduce_rows<<<N2 / 128, 128, 0, stream>>>(P, pos, (float*)d_out);
}